// Round 7
// baseline (843.669 us; speedup 1.0000x reference)
//
#include <hip/hip_runtime.h>

#define LL 784
#define CHI 128
#define CLS 10
#define BC 32
#define NBLK 32          // 1024/32

typedef __attribute__((ext_vector_type(8))) short short8;
typedef __attribute__((ext_vector_type(4))) float floatx4;

__device__ inline unsigned int f2bf(float v) {
    unsigned int u = __float_as_uint(v);
    u += 0x7fffu + ((u >> 16) & 1u);   // RNE
    return u >> 16;
}

// workgroup barrier that does NOT drain vmcnt — keeps W prefetch in flight.
__device__ inline void lds_barrier() {
    asm volatile("s_waitcnt lgkmcnt(0)\n\ts_barrier" ::: "memory");
}

// packed fp32x2 -> bf16x2 (RNE), lo = first arg
__device__ inline unsigned int cvt_pk_bf16(float lo, float hi) {
    unsigned int r;
    asm("v_cvt_pk_bf16_f32 %0, %1, %2" : "=v"(r) : "v"(lo), "v"(hi));
    return r;
}

// un-sinkable 16B global load (volatile asm pins issue position). NO cache
// flags: `nt` is the prime suspect for rounds 5/6 container failures.
template <int OFF>
__device__ inline short8 gload(const char* p) {
    short8 r;
    asm volatile("global_load_dwordx4 %0, %1, off offset:%2"
                 : "=v"(r) : "v"(p), "i"(OFF));
    return r;
}

__device__ inline floatx4 gloadf4(const float* p) {
    floatx4 r;
    asm volatile("global_load_dwordx4 %0, %1, off"
                 : "=v"(r) : "v"(p));
    return r;
}

// counted waits (round-3-verified depth-2 scheme). sched_barrier stops MFMA
// hoisting above the wait (rule #18).
__device__ inline void vm_wait8() {
    asm volatile("s_waitcnt vmcnt(8)" ::: "memory");
    __builtin_amdgcn_sched_barrier(0);
}
__device__ inline void vm_wait0() {
    asm volatile("s_waitcnt vmcnt(0)" ::: "memory");
    __builtin_amdgcn_sched_barrier(0);
}

// ---------------------------------------------------------------------------
// prep: W fp32 (L,2,CHI,CHI) -> bf16 MFMA fragments via LDS transpose.
// UNCHANGED (layout verified by passing rounds).
// ws uint4 index: (((n*8 + nt)*2 + s)*4 + kt)*64 + l
//   lane l elem j: value = W[n][s][a = kt*32 + (l>>4)*8 + j][c = nt*16 + (l&15)]
// ---------------------------------------------------------------------------
__global__ __launch_bounds__(256) void prep_kernel(const float* __restrict__ W,
                                                   uint4* __restrict__ ws4) {
    __shared__ float tile[32 * 132];
    const int b = blockIdx.x;            // n*8 + s*4 + kt
    const int n = b >> 3, s = (b >> 2) & 1, kt = b & 3;
    const float* Wp = W + ((size_t)(n * 2 + s) * CHI + kt * 32) * CHI;
    const int t = threadIdx.x;
    #pragma unroll
    for (int k = 0; k < 4; k++) {
        int v = t + k * 256;             // 0..1023 float4s
        int a = v >> 5, c4 = v & 31;
        float4 val = *(const float4*)(Wp + a * CHI + c4 * 4);
        *(float4*)&tile[a * 132 + c4 * 4] = val;
    }
    __syncthreads();
    const int l = t & 63, f0 = t >> 6;
    const int m_ = l & 15, q_ = l >> 4;
    #pragma unroll
    for (int ff = 0; ff < 2; ff++) {
        int nt = f0 + ff * 4;
        const float* tp = &tile[(q_ * 8) * 132 + nt * 16 + m_];
        uint4 pk;
        pk.x = f2bf(tp[0 * 132]) | (f2bf(tp[1 * 132]) << 16);
        pk.y = f2bf(tp[2 * 132]) | (f2bf(tp[3 * 132]) << 16);
        pk.z = f2bf(tp[4 * 132]) | (f2bf(tp[5 * 132]) << 16);
        pk.w = f2bf(tp[6 * 132]) | (f2bf(tp[7 * 132]) << 16);
        ws4[(size_t)(((n * 8 + nt) * 2 + s) * 4 + kt) * 64 + l] = pk;
    }
}

// ---------------------------------------------------------------------------
// main: 32 blocks x 512 threads (8 waves). BC=32 batch rows per block —
// HALF the W streams of the BC=16 version. A/B on the aggregate-L3-BW theory:
// per-CU W bytes/site unchanged (64 KB), aggregate demand halves (6.2->3.1
// TB/s). Wave w owns c-tile nt=w; TWO b-halves per wave (b=m and b=m+16):
// 16 MFMAs/site, hacc0/hacc1. B-frags bfbuf[par][kt][bhalf][lane] (16 KB).
// W: depth-2 register pipeline + per-site vmcnt(8) (round-3-verified).
// ---------------------------------------------------------------------------
__global__ __launch_bounds__(512) void mps_kernel(const float* __restrict__ x,
                                                  const unsigned short* __restrict__ ws,
                                                  const float* __restrict__ V,
                                                  float* __restrict__ out) {
    __shared__ short8 bfbuf[2][4][2][64];  // [par][kt][bhalf][lane], 16 KB
    __shared__ float hfin[BC * 136];       // final h for h@V

    const int t = threadIdx.x;
    const int w = t >> 6, l = t & 63;
    const int m = l & 15, q = l >> 4;
    const int rb = blockIdx.x * BC;

    // init bfbuf[0] = bf16(1.0)  (par 0 = 8 KB = 2048 uints)
    for (int i = t; i < 2048; i += 512)
        ((unsigned int*)&bfbuf[0][0][0][0])[i] = 0x3F803F80u;

    // ---- x: per-lane registers; row-set 0: b = m, row-set 1: b = m+16 ----
    const float* xp0 = x + (size_t)(rb + m) * (2 * LL);        // R0 s=0
    const float* xp1 = xp0 + LL;                               // R0 s=1
    const float* xp2 = x + (size_t)(rb + 16 + m) * (2 * LL);   // R1 s=0
    const float* xp3 = xp2 + LL;                               // R1 s=1
    floatx4 xA0, xA1, xA2, xA3, xB0, xB1, xB2, xB3;
    floatx4 xC0, xC1, xC2, xC3, xD0, xD1, xD2, xD3;
    xA0 = gloadf4(xp0 + 0);  xA1 = gloadf4(xp0 + 4);
    xA2 = gloadf4(xp1 + 0);  xA3 = gloadf4(xp1 + 4);
    xC0 = gloadf4(xp2 + 0);  xC1 = gloadf4(xp2 + 4);
    xC2 = gloadf4(xp3 + 0);  xC3 = gloadf4(xp3 + 4);

    // ---- W: wave-private byte base; frag f=s*4+kt at +f*1024, site at +n*65536
    const char* wsb = (const char*)ws + (size_t)w * 8192 + (size_t)l * 16;

    short8 bWA[8], bWB[8];
#define LOAD_BATCH(BUF, PTR) do {                                   \
    const char* p_ = (PTR);                                         \
    BUF[0] = gload<0>(p_);           BUF[1] = gload<1024>(p_);      \
    BUF[2] = gload<2048>(p_);        BUF[3] = gload<3072>(p_);      \
    BUF[4] = gload<0>(p_ + 4096);    BUF[5] = gload<1024>(p_ + 4096); \
    BUF[6] = gload<2048>(p_ + 4096); BUF[7] = gload<3072>(p_ + 4096); \
} while (0)

    LOAD_BATCH(bWA, wsb);
    LOAD_BATCH(bWB, wsb + 65536);

    floatx4 hacc0 = (floatx4){1.f, 1.f, 1.f, 1.f};   // b = m,     a = w*16+q*4+i
    floatx4 hacc1 = (floatx4){1.f, 1.f, 1.f, 1.f};   // b = m+16,  same a

    // h ds_write target (verified mapping, extended by bhalf):
    // value (b, a): frag kt=a>>5=w>>1, bhalf = b>>4, lane' = (b&15) +
    // 16*((w&1)*2+(q>>1)), dwords (q&1)*2 + {0,1}. par stride = 2048 dwords.
    unsigned int* const bfw = (unsigned int*)&bfbuf[0][0][0][0];
    const int l2 = m + 16 * ((w & 1) * 2 + (q >> 1));
    const int wr_dw = ((w >> 1) * 2) * 256 + l2 * 4 + (q & 1) * 2;   // bhalf 0; +256 for bhalf 1

    __syncthreads();

// PF: 1 -> prefetch W(NN+2) into WBUF; WAIT: vm_wait8 or vm_wait0
#define SITE_BODY(NN, PAR, WBUF, X0, X1, X2, X3, PF, WAIT) do {                       \
    lds_barrier();                                                                    \
    short8 bf00 = bfbuf[PAR][0][0][l];                                                \
    short8 bf10 = bfbuf[PAR][1][0][l];                                                \
    short8 bf20 = bfbuf[PAR][2][0][l];                                                \
    short8 bf30 = bfbuf[PAR][3][0][l];                                                \
    short8 bf01 = bfbuf[PAR][0][1][l];                                                \
    short8 bf11 = bfbuf[PAR][1][1][l];                                                \
    short8 bf21 = bfbuf[PAR][2][1][l];                                                \
    short8 bf31 = bfbuf[PAR][3][1][l];                                                \
    WAIT();                                                                           \
    floatx4 z = (floatx4){0.f, 0.f, 0.f, 0.f};                                        \
    floatx4 pA0 = __builtin_amdgcn_mfma_f32_16x16x32_bf16(WBUF[0], bf00, z, 0, 0, 0); \
    floatx4 pA1 = __builtin_amdgcn_mfma_f32_16x16x32_bf16(WBUF[2], bf20, z, 0, 0, 0); \
    floatx4 qA0 = __builtin_amdgcn_mfma_f32_16x16x32_bf16(WBUF[4], bf00, z, 0, 0, 0); \
    floatx4 qA1 = __builtin_amdgcn_mfma_f32_16x16x32_bf16(WBUF[6], bf20, z, 0, 0, 0); \
    floatx4 pB0 = __builtin_amdgcn_mfma_f32_16x16x32_bf16(WBUF[0], bf01, z, 0, 0, 0); \
    floatx4 pB1 = __builtin_amdgcn_mfma_f32_16x16x32_bf16(WBUF[2], bf21, z, 0, 0, 0); \
    floatx4 qB0 = __builtin_amdgcn_mfma_f32_16x16x32_bf16(WBUF[4], bf01, z, 0, 0, 0); \
    floatx4 qB1 = __builtin_amdgcn_mfma_f32_16x16x32_bf16(WBUF[6], bf21, z, 0, 0, 0); \
    pA0 = __builtin_amdgcn_mfma_f32_16x16x32_bf16(WBUF[1], bf10, pA0, 0, 0, 0);       \
    pA1 = __builtin_amdgcn_mfma_f32_16x16x32_bf16(WBUF[3], bf30, pA1, 0, 0, 0);       \
    qA0 = __builtin_amdgcn_mfma_f32_16x16x32_bf16(WBUF[5], bf10, qA0, 0, 0, 0);       \
    qA1 = __builtin_amdgcn_mfma_f32_16x16x32_bf16(WBUF[7], bf30, qA1, 0, 0, 0);       \
    pB0 = __builtin_amdgcn_mfma_f32_16x16x32_bf16(WBUF[1], bf11, pB0, 0, 0, 0);       \
    pB1 = __builtin_amdgcn_mfma_f32_16x16x32_bf16(WBUF[3], bf31, pB1, 0, 0, 0);       \
    qB0 = __builtin_amdgcn_mfma_f32_16x16x32_bf16(WBUF[5], bf11, qB0, 0, 0, 0);       \
    qB1 = __builtin_amdgcn_mfma_f32_16x16x32_bf16(WBUF[7], bf31, qB1, 0, 0, 0);       \
    if (PF) LOAD_BATCH(WBUF, wsb + (size_t)((NN) + 2) * 65536);                       \
    _Pragma("unroll")                                                                 \
    for (int i = 0; i < 4; i++) {                                                     \
        hacc0[i] += (X0) * (pA0[i] + pA1[i]) + (X1) * (qA0[i] + qA1[i]);              \
        hacc1[i] += (X2) * (pB0[i] + pB1[i]) + (X3) * (qB0[i] + qB1[i]);              \
    }                                                                                 \
    uint2 pk0, pk1;                                                                   \
    pk0.x = cvt_pk_bf16(hacc0[0], hacc0[1]);                                          \
    pk0.y = cvt_pk_bf16(hacc0[2], hacc0[3]);                                          \
    pk1.x = cvt_pk_bf16(hacc1[0], hacc1[1]);                                          \
    pk1.y = cvt_pk_bf16(hacc1[2], hacc1[3]);                                          \
    *(uint2*)&bfw[((PAR) ^ 1) * 2048 + wr_dw]       = pk0;                            \
    *(uint2*)&bfw[((PAR) ^ 1) * 2048 + 256 + wr_dw] = pk1;                            \
} while (0)

    // main loop: sites 0..767 — steady state, vmcnt(8), always prefetch
    for (int nb = 0; nb < LL - 16; nb += 16) {
        xB0 = gloadf4(xp0 + nb + 8);
        xB1 = gloadf4(xp0 + nb + 12);
        xB2 = gloadf4(xp1 + nb + 8);
        xB3 = gloadf4(xp1 + nb + 12);
        xD0 = gloadf4(xp2 + nb + 8);
        xD1 = gloadf4(xp2 + nb + 12);
        xD2 = gloadf4(xp3 + nb + 8);
        xD3 = gloadf4(xp3 + nb + 12);
        SITE_BODY(nb + 0,  0, bWA, xA0[0], xA2[0], xC0[0], xC2[0], 1, vm_wait8);
        SITE_BODY(nb + 1,  1, bWB, xA0[1], xA2[1], xC0[1], xC2[1], 1, vm_wait8);
        SITE_BODY(nb + 2,  0, bWA, xA0[2], xA2[2], xC0[2], xC2[2], 1, vm_wait8);
        SITE_BODY(nb + 3,  1, bWB, xA0[3], xA2[3], xC0[3], xC2[3], 1, vm_wait8);
        SITE_BODY(nb + 4,  0, bWA, xA1[0], xA3[0], xC1[0], xC3[0], 1, vm_wait8);
        SITE_BODY(nb + 5,  1, bWB, xA1[1], xA3[1], xC1[1], xC3[1], 1, vm_wait8);
        SITE_BODY(nb + 6,  0, bWA, xA1[2], xA3[2], xC1[2], xC3[2], 1, vm_wait8);
        SITE_BODY(nb + 7,  1, bWB, xA1[3], xA3[3], xC1[3], xC3[3], 1, vm_wait8);
        xA0 = gloadf4(xp0 + nb + 16);
        xA1 = gloadf4(xp0 + nb + 20);
        xA2 = gloadf4(xp1 + nb + 16);
        xA3 = gloadf4(xp1 + nb + 20);
        xC0 = gloadf4(xp2 + nb + 16);
        xC1 = gloadf4(xp2 + nb + 20);
        xC2 = gloadf4(xp3 + nb + 16);
        xC3 = gloadf4(xp3 + nb + 20);
        SITE_BODY(nb + 8,  0, bWA, xB0[0], xB2[0], xD0[0], xD2[0], 1, vm_wait8);
        SITE_BODY(nb + 9,  1, bWB, xB0[1], xB2[1], xD0[1], xD2[1], 1, vm_wait8);
        SITE_BODY(nb + 10, 0, bWA, xB0[2], xB2[2], xD0[2], xD2[2], 1, vm_wait8);
        SITE_BODY(nb + 11, 1, bWB, xB0[3], xB2[3], xD0[3], xD2[3], 1, vm_wait8);
        SITE_BODY(nb + 12, 0, bWA, xB1[0], xB3[0], xD1[0], xD3[0], 1, vm_wait8);
        SITE_BODY(nb + 13, 1, bWB, xB1[1], xB3[1], xD1[1], xD3[1], 1, vm_wait8);
        SITE_BODY(nb + 14, 0, bWA, xB1[2], xB3[2], xD1[2], xD3[2], 1, vm_wait8);
        SITE_BODY(nb + 15, 1, bWB, xB1[3], xB3[3], xD1[3], xD3[3], 1, vm_wait8);
    }

    // peeled tail: sites 768..783. PF while NN+2 <= 783; last two drain 8 -> 0.
    xB0 = gloadf4(xp0 + 768 + 8);
    xB1 = gloadf4(xp0 + 768 + 12);
    xB2 = gloadf4(xp1 + 768 + 8);
    xB3 = gloadf4(xp1 + 768 + 12);
    xD0 = gloadf4(xp2 + 768 + 8);
    xD1 = gloadf4(xp2 + 768 + 12);
    xD2 = gloadf4(xp3 + 768 + 8);
    xD3 = gloadf4(xp3 + 768 + 12);
    SITE_BODY(768, 0, bWA, xA0[0], xA2[0], xC0[0], xC2[0], 1, vm_wait8);
    SITE_BODY(769, 1, bWB, xA0[1], xA2[1], xC0[1], xC2[1], 1, vm_wait8);
    SITE_BODY(770, 0, bWA, xA0[2], xA2[2], xC0[2], xC2[2], 1, vm_wait8);
    SITE_BODY(771, 1, bWB, xA0[3], xA2[3], xC0[3], xC2[3], 1, vm_wait8);
    SITE_BODY(772, 0, bWA, xA1[0], xA3[0], xC1[0], xC3[0], 1, vm_wait8);
    SITE_BODY(773, 1, bWB, xA1[1], xA3[1], xC1[1], xC3[1], 1, vm_wait8);
    SITE_BODY(774, 0, bWA, xA1[2], xA3[2], xC1[2], xC3[2], 1, vm_wait8);
    SITE_BODY(775, 1, bWB, xA1[3], xA3[3], xC1[3], xC3[3], 1, vm_wait8);
    SITE_BODY(776, 0, bWA, xB0[0], xB2[0], xD0[0], xD2[0], 1, vm_wait8);
    SITE_BODY(777, 1, bWB, xB0[1], xB2[1], xD0[1], xD2[1], 1, vm_wait8);
    SITE_BODY(778, 0, bWA, xB0[2], xB2[2], xD0[2], xD2[2], 1, vm_wait8);
    SITE_BODY(779, 1, bWB, xB0[3], xB2[3], xD0[3], xD2[3], 1, vm_wait8);
    SITE_BODY(780, 0, bWA, xB1[0], xB3[0], xD1[0], xD3[0], 1, vm_wait8);
    SITE_BODY(781, 1, bWB, xB1[1], xB3[1], xD1[1], xD3[1], 1, vm_wait8);
    SITE_BODY(782, 0, bWA, xB1[2], xB3[2], xD1[2], xD3[2], 0, vm_wait8);
    SITE_BODY(783, 1, bWB, xB1[3], xB3[3], xD1[3], xD3[3], 0, vm_wait0);
#undef SITE_BODY
#undef LOAD_BATCH

    // hacc (exact fp32) -> LDS, then logits = h @ V
    *(floatx4*)&hfin[m * 136 + w * 16 + q * 4]        = hacc0;
    *(floatx4*)&hfin[(m + 16) * 136 + w * 16 + q * 4] = hacc1;
    __syncthreads();

    if (t < BC * CLS) {
        int r = t / CLS, cls = t % CLS;
        float sum = 0.f;
        for (int a = 0; a < CHI; a++) sum += hfin[r * 136 + a] * V[a * CLS + cls];
        out[(size_t)(rb + r) * CLS + cls] = sum;
    }
}

extern "C" void kernel_launch(void* const* d_in, const int* in_sizes, int n_in,
                              void* d_out, int out_size, void* d_ws, size_t ws_size,
                              hipStream_t stream) {
    const float* x = (const float*)d_in[0];
    const float* W = (const float*)d_in[1];
    const float* V = (const float*)d_in[2];
    float* out = (float*)d_out;

    prep_kernel<<<LL * 8, 256, 0, stream>>>(W, (uint4*)d_ws);
    mps_kernel<<<NBLK, 512, 0, stream>>>(x, (const unsigned short*)d_ws, V, out);
}

// Round 9
// 774.903 us; speedup vs baseline: 1.0887x; 1.0887x over previous
//
#include <hip/hip_runtime.h>

#define LL 784
#define CHI 128
#define CLS 10
#define BC 16
#define NBLK 64          // 1024/16

typedef __attribute__((ext_vector_type(4))) float floatx4;
typedef __attribute__((ext_vector_type(2))) long lng2;

// ---------------------------------------------------------------------------
// fp8 e4m3fn packing (RNE), manual integer path ONLY (no fp8-cvt builtins —
// r8 crash suspect). Flush below 2^-6, saturate at 448; both harmless at our
// operand scales (|256W| ~ 0.2, |16d| ~ 1.6).
// ---------------------------------------------------------------------------
__device__ inline unsigned int f2fp8(float v) {
    unsigned int u = __float_as_uint(v);
    unsigned int s = (u >> 24) & 0x80u;
    unsigned int a = u & 0x7fffffffu;
    if (a >= 0x43e00000u) return s | 0x7Eu;   // >= 448 -> max finite
    if (a <  0x3c800000u) return s;           // < 2^-6 -> flush to 0
    unsigned int r = a + 0x0007ffffu + ((a >> 20) & 1u);   // RNE at bit 20
    if (r >= 0x43e00000u) return s | 0x7Eu;
    unsigned int E = (r >> 23) - 120u;        // 1..15
    return s | (E << 3) | ((r >> 20) & 7u);
}

__device__ inline unsigned int pk4_fp8(float v0, float v1, float v2, float v3) {
    return f2fp8(v0) | (f2fp8(v1) << 8) | (f2fp8(v2) << 16) | (f2fp8(v3) << 24);
}

// workgroup barrier that does NOT drain vmcnt — keeps W prefetch in flight.
__device__ inline void lds_barrier() {
    asm volatile("s_waitcnt lgkmcnt(0)\n\ts_barrier" ::: "memory");
}

// un-sinkable global loads: volatile asm pins the ISSUE position.
// 16B form identical to rounds 3/4/7 (harness-verified); result typed lng2
// so MFMA consumes 64-bit elements directly.
template <int OFF>
__device__ inline lng2 gload16(const char* p) {
    lng2 r;
    asm volatile("global_load_dwordx4 %0, %1, off offset:%2"
                 : "=v"(r) : "v"(p), "i"(OFF));
    return r;
}
template <int OFF>
__device__ inline floatx4 gloadf4o(const float* p) {
    floatx4 r;
    asm volatile("global_load_dwordx4 %0, %1, off offset:%2"
                 : "=v"(r) : "v"(p), "i"(OFF));
    return r;
}
__device__ inline floatx4 gloadf4(const float* p) {
    floatx4 r;
    asm volatile("global_load_dwordx4 %0, %1, off"
                 : "=v"(r) : "v"(p));
    return r;
}

// counted waits; sched_barrier stops register-only ops hoisting above (rule #18).
// Batch = 6 loads (4 W + 2 R), issued 2 sites ahead. Steady FIFO at site n's
// wait: [batch(n+1)] or [batch(n+1), x4] newest -> vmcnt(6)/vmcnt(10).
// Prologue site 0: [xA4, batch0, batch1, xB4]=20 -> wait10 retires xA+batch0.
// Tail drains 6 -> 0.
__device__ inline void vm_wait10() {
    asm volatile("s_waitcnt vmcnt(10)" ::: "memory");
    __builtin_amdgcn_sched_barrier(0);
}
__device__ inline void vm_wait6() {
    asm volatile("s_waitcnt vmcnt(6)" ::: "memory");
    __builtin_amdgcn_sched_barrier(0);
}
__device__ inline void vm_wait0() {
    asm volatile("s_waitcnt vmcnt(0)" ::: "memory");
    __builtin_amdgcn_sched_barrier(0);
}

// ---------------------------------------------------------------------------
// prep: W fp32 (L,2,CHI,CHI) -> fp8 e4m3 MFMA A-fragments, scaled by 2^8.
// Same (lane,elem)->(a,c) map as the verified bf16 prep; 1 byte/elem.
// Frag f = s*4+kt (512 B each) stored PAIRED so mps reads dwordx4 per pair:
//   byte addr = n*32768 + nt*4096 + (f>>1)*1024 + l*16 + (f&1)*8
//   byte e of frag f lane l = fp8(256 * W[n][s][a=kt*32+(l>>4)*8+e][c=nt*16+(l&15)])
// ---------------------------------------------------------------------------
__global__ __launch_bounds__(256) void prep_kernel(const float* __restrict__ W,
                                                   unsigned char* __restrict__ ws8) {
    __shared__ float tile[32 * 132];
    const int b = blockIdx.x;            // n*8 + s*4 + kt
    const int n = b >> 3, s = (b >> 2) & 1, kt = b & 3;
    const float* Wp = W + ((size_t)(n * 2 + s) * CHI + kt * 32) * CHI;
    const int t = threadIdx.x;
    #pragma unroll
    for (int k = 0; k < 4; k++) {
        int v = t + k * 256;             // 0..1023 float4s
        int a = v >> 5, c4 = v & 31;
        float4 val = *(const float4*)(Wp + a * CHI + c4 * 4);
        *(float4*)&tile[a * 132 + c4 * 4] = val;
    }
    __syncthreads();
    const int l = t & 63, f0 = t >> 6;
    const int m_ = l & 15, q_ = l >> 4;
    const int f = s * 4 + kt;
    #pragma unroll
    for (int ff = 0; ff < 2; ff++) {
        int nt = f0 + ff * 4;
        const float* tp = &tile[(q_ * 8) * 132 + nt * 16 + m_];
        unsigned int dw0 = pk4_fp8(tp[0 * 132] * 256.f, tp[1 * 132] * 256.f,
                                   tp[2 * 132] * 256.f, tp[3 * 132] * 256.f);
        unsigned int dw1 = pk4_fp8(tp[4 * 132] * 256.f, tp[5 * 132] * 256.f,
                                   tp[6 * 132] * 256.f, tp[7 * 132] * 256.f);
        size_t addr = (size_t)n * 32768 + (size_t)nt * 4096 + (f >> 1) * 1024
                    + l * 16 + (f & 1) * 8;
        uint2 pk; pk.x = dw0; pk.y = dw1;
        *(uint2*)(ws8 + addr) = pk;
    }
}

// ---------------------------------------------------------------------------
// prepR: R[n][s][c] = sum_a W[n][s][a][c]  (fp32, exact "mean-field" path).
// ---------------------------------------------------------------------------
__global__ __launch_bounds__(256) void prepR_kernel(const float* __restrict__ W,
                                                    float* __restrict__ R) {
    const int n = blockIdx.x, t = threadIdx.x;
    const int s = t >> 7, c = t & 127;
    const float* Wp = W + ((size_t)(n * 2 + s) * CHI) * CHI + c;
    float sum = 0.f;
    #pragma unroll 8
    for (int a = 0; a < CHI; a++) sum += Wp[(size_t)a * CHI];
    R[(n * 2 + s) * CHI + c] = sum;
}

// ---------------------------------------------------------------------------
// main: 64 blocks x 512 threads (8 waves). Residual form h = 1 + d:
//   h'[c][b] = h[c][b] + sum_s x[b][s] * ( R[n][s][c] + sum_a W[a][c] d[b][a] )
// A = fp8 W-frags (x2^8), B = fp8 d-frags (x2^4) in LDS ping-pong; MFMA
// output descaled by 2^-12. hacc holds exact fp32 h. W stream HALVED:
// 32 KB/site/CU (512 lines ~ 512 cy at the ~1 line/cy TCP wall, vs 1024).
// LDS exchange halved: 4 ds_read_b64 + 1 ds_write_b32 per thread per site.
// ---------------------------------------------------------------------------
__global__ __launch_bounds__(512) void mps_kernel(const float* __restrict__ x,
                                                  const unsigned char* __restrict__ ws8,
                                                  const float* __restrict__ R,
                                                  const float* __restrict__ V,
                                                  float* __restrict__ out) {
    __shared__ long bfb[2][4][64];       // [par][kt][lane] fp8 d-frags, 4 KB
    __shared__ float hfin[BC * 136];     // final h for h@V

    const int t = threadIdx.x;
    const int w = t >> 6, l = t & 63;
    const int m = l & 15, q = l >> 4;
    const int rb = blockIdx.x * BC;

    // init d(0) = 0: zero par 0 (256 longs)
    for (int i = t; i < 256; i += 512) ((long*)bfb)[i] = 0L;

    // ---- x: per-lane registers, batch row b = m ----
    const float* xp0 = x + (size_t)(rb + m) * (2 * LL);   // s = 0
    const float* xp1 = xp0 + LL;                          // s = 1
    floatx4 xA0, xA1, xA2, xA3, xB0, xB1, xB2, xB3;
    xA0 = gloadf4(xp0 + 0);  xA1 = gloadf4(xp0 + 4);
    xA2 = gloadf4(xp1 + 0);  xA3 = gloadf4(xp1 + 4);

    // ---- W/R bases ----
    const char* wsb = (const char*)ws8 + (size_t)w * 4096 + (size_t)l * 16;
    const float* rbase = R + w * 16 + q * 4;              // + n*256 (+128 for s=1)

    lng2 bWA[4], bWB[4];
    floatx4 rA0, rA1, rB0, rB1;
#define LOAD_BATCH(WB_, R0_, R1_, NT_) do {                         \
    const char* p_ = wsb + (size_t)(NT_) * 32768;                   \
    WB_[0] = gload16<0>(p_);     WB_[1] = gload16<1024>(p_);        \
    WB_[2] = gload16<2048>(p_);  WB_[3] = gload16<3072>(p_);        \
    const float* rp_ = rbase + (NT_) * 256;                         \
    R0_ = gloadf4o<0>(rp_);  R1_ = gloadf4o<512>(rp_);              \
} while (0)

    LOAD_BATCH(bWA, rA0, rA1, 0);
    LOAD_BATCH(bWB, rB0, rB1, 1);

    floatx4 hacc = (floatx4){1.f, 1.f, 1.f, 1.f};   // c = w*16 + q*4 + i, b = m

    // d ds_write target (same verified mapping as bf16 h-exchange, b32):
    // value (b=m, a=w*16+q*4+i) -> frag kt=w>>1, lane' = m+16*((w&1)*2+(q>>1)),
    // dword slot q&1, byte i. par stride 512 dw, kt stride 128 dw.
    unsigned int* const bfw = (unsigned int*)&bfb[0][0][0];
    const int wr_dw = (w >> 1) * 128 + (m + 16 * ((w & 1) * 2 + (q >> 1))) * 2 + (q & 1);

    __syncthreads();

#define MFMA8(A, B, C) __builtin_amdgcn_mfma_f32_16x16x32_fp8_fp8((A), (B), (C), 0, 0, 0)

// PF: 1 -> prefetch batch(NN+2); WAIT: vm_wait10 / vm_wait6 / vm_wait0
#define SITE_BODY(NN, PAR, WBUF, RB0_, RB1_, X0, X1, PF, WAIT) do {                 \
    lds_barrier();                                                                  \
    long d0 = bfb[PAR][0][l];                                                       \
    long d1 = bfb[PAR][1][l];                                                       \
    long d2 = bfb[PAR][2][l];                                                       \
    long d3 = bfb[PAR][3][l];                                                       \
    WAIT();                                                                         \
    floatx4 r0 = RB0_, r1 = RB1_;       /* copy before refill overwrites */         \
    floatx4 z = (floatx4){0.f, 0.f, 0.f, 0.f};                                      \
    floatx4 p0 = MFMA8(WBUF[0][0], d0, z);                                          \
    floatx4 p1 = MFMA8(WBUF[2][0], d0, z);                                          \
    p0 = MFMA8(WBUF[0][1], d1, p0);                                                 \
    p1 = MFMA8(WBUF[2][1], d1, p1);                                                 \
    p0 = MFMA8(WBUF[1][0], d2, p0);                                                 \
    p1 = MFMA8(WBUF[3][0], d2, p1);                                                 \
    p0 = MFMA8(WBUF[1][1], d3, p0);                                                 \
    p1 = MFMA8(WBUF[3][1], d3, p1);                                                 \
    if (PF) LOAD_BATCH(WBUF, RB0_, RB1_, (NN) + 2);                                 \
    float X0s = (X0) * 2.44140625e-4f, X1s = (X1) * 2.44140625e-4f;                 \
    _Pragma("unroll")                                                               \
    for (int i = 0; i < 4; i++)                                                     \
        hacc[i] += (X0) * r0[i] + (X1) * r1[i] + X0s * p0[i] + X1s * p1[i];         \
    float e0 = hacc[0] * 16.f - 16.f, e1 = hacc[1] * 16.f - 16.f;                   \
    float e2 = hacc[2] * 16.f - 16.f, e3 = hacc[3] * 16.f - 16.f;                   \
    bfw[((PAR) ^ 1) * 512 + wr_dw] = pk4_fp8(e0, e1, e2, e3);                       \
} while (0)

    // main loop: sites 0..767 — steady state
    for (int nb = 0; nb < LL - 16; nb += 16) {
        xB0 = gloadf4(xp0 + nb + 8);
        xB1 = gloadf4(xp0 + nb + 12);
        xB2 = gloadf4(xp1 + nb + 8);
        xB3 = gloadf4(xp1 + nb + 12);
        SITE_BODY(nb + 0,  0, bWA, rA0, rA1, xA0[0], xA2[0], 1, vm_wait10);
        SITE_BODY(nb + 1,  1, bWB, rB0, rB1, xA0[1], xA2[1], 1, vm_wait6);
        SITE_BODY(nb + 2,  0, bWA, rA0, rA1, xA0[2], xA2[2], 1, vm_wait6);
        SITE_BODY(nb + 3,  1, bWB, rB0, rB1, xA0[3], xA2[3], 1, vm_wait6);
        SITE_BODY(nb + 4,  0, bWA, rA0, rA1, xA1[0], xA3[0], 1, vm_wait6);
        SITE_BODY(nb + 5,  1, bWB, rB0, rB1, xA1[1], xA3[1], 1, vm_wait6);
        SITE_BODY(nb + 6,  0, bWA, rA0, rA1, xA1[2], xA3[2], 1, vm_wait6);
        SITE_BODY(nb + 7,  1, bWB, rB0, rB1, xA1[3], xA3[3], 1, vm_wait6);
        xA0 = gloadf4(xp0 + nb + 16);
        xA1 = gloadf4(xp0 + nb + 20);
        xA2 = gloadf4(xp1 + nb + 16);
        xA3 = gloadf4(xp1 + nb + 20);
        SITE_BODY(nb + 8,  0, bWA, rA0, rA1, xB0[0], xB2[0], 1, vm_wait10);
        SITE_BODY(nb + 9,  1, bWB, rB0, rB1, xB0[1], xB2[1], 1, vm_wait6);
        SITE_BODY(nb + 10, 0, bWA, rA0, rA1, xB0[2], xB2[2], 1, vm_wait6);
        SITE_BODY(nb + 11, 1, bWB, rB0, rB1, xB0[3], xB2[3], 1, vm_wait6);
        SITE_BODY(nb + 12, 0, bWA, rA0, rA1, xB1[0], xB3[0], 1, vm_wait6);
        SITE_BODY(nb + 13, 1, bWB, rB0, rB1, xB1[1], xB3[1], 1, vm_wait6);
        SITE_BODY(nb + 14, 0, bWA, rA0, rA1, xB1[2], xB3[2], 1, vm_wait6);
        SITE_BODY(nb + 15, 1, bWB, rB0, rB1, xB1[3], xB3[3], 1, vm_wait6);
    }

    // peeled tail: sites 768..783 (xA covers 768-775, loaded in last iter)
    xB0 = gloadf4(xp0 + 768 + 8);
    xB1 = gloadf4(xp0 + 768 + 12);
    xB2 = gloadf4(xp1 + 768 + 8);
    xB3 = gloadf4(xp1 + 768 + 12);
    SITE_BODY(768, 0, bWA, rA0, rA1, xA0[0], xA2[0], 1, vm_wait10);   // PF 770
    SITE_BODY(769, 1, bWB, rB0, rB1, xA0[1], xA2[1], 1, vm_wait6);    // PF 771
    SITE_BODY(770, 0, bWA, rA0, rA1, xA0[2], xA2[2], 1, vm_wait6);    // PF 772
    SITE_BODY(771, 1, bWB, rB0, rB1, xA0[3], xA2[3], 1, vm_wait6);    // PF 773
    SITE_BODY(772, 0, bWA, rA0, rA1, xA1[0], xA3[0], 1, vm_wait6);    // PF 774
    SITE_BODY(773, 1, bWB, rB0, rB1, xA1[1], xA3[1], 1, vm_wait6);    // PF 775
    SITE_BODY(774, 0, bWA, rA0, rA1, xA1[2], xA3[2], 1, vm_wait6);    // PF 776
    SITE_BODY(775, 1, bWB, rB0, rB1, xA1[3], xA3[3], 1, vm_wait6);    // PF 777
    SITE_BODY(776, 0, bWA, rA0, rA1, xB0[0], xB2[0], 1, vm_wait10);   // PF 778
    SITE_BODY(777, 1, bWB, rB0, rB1, xB0[1], xB2[1], 1, vm_wait6);    // PF 779
    SITE_BODY(778, 0, bWA, rA0, rA1, xB0[2], xB2[2], 1, vm_wait6);    // PF 780
    SITE_BODY(779, 1, bWB, rB0, rB1, xB0[3], xB2[3], 1, vm_wait6);    // PF 781
    SITE_BODY(780, 0, bWA, rA0, rA1, xB1[0], xB3[0], 1, vm_wait6);    // PF 782
    SITE_BODY(781, 1, bWB, rB0, rB1, xB1[1], xB3[1], 1, vm_wait6);    // PF 783
    SITE_BODY(782, 0, bWA, rA0, rA1, xB1[2], xB3[2], 0, vm_wait6);
    SITE_BODY(783, 1, bWB, rB0, rB1, xB1[3], xB3[3], 0, vm_wait0);
#undef SITE_BODY
#undef LOAD_BATCH
#undef MFMA8

    // hacc (exact fp32 h) -> LDS, then logits = h @ V
    *(floatx4*)&hfin[m * 136 + w * 16 + q * 4] = hacc;
    __syncthreads();

    if (t < BC * CLS) {
        int r = t / CLS, cls = t % CLS;
        float sum = 0.f;
        for (int a = 0; a < CHI; a++) sum += hfin[r * 136 + a] * V[a * CLS + cls];
        out[(size_t)(rb + r) * CLS + cls] = sum;
    }
}

extern "C" void kernel_launch(void* const* d_in, const int* in_sizes, int n_in,
                              void* d_out, int out_size, void* d_ws, size_t ws_size,
                              hipStream_t stream) {
    const float* x = (const float*)d_in[0];
    const float* W = (const float*)d_in[1];
    const float* V = (const float*)d_in[2];
    float* out = (float*)d_out;

    unsigned char* ws8 = (unsigned char*)d_ws;                 // 784*32768 = 25.7 MB
    float* R = (float*)(ws8 + (size_t)LL * 32768);             // 784*256*4 = 0.8 MB

    prep_kernel<<<LL * 8, 256, 0, stream>>>(W, ws8);
    prepR_kernel<<<LL, 256, 0, stream>>>(W, R);
    mps_kernel<<<NBLK, 512, 0, stream>>>(x, ws8, R, V, out);
}